// Round 3
// 167.081 us; speedup vs baseline: 1.1494x; 1.1494x over previous
//
#include <hip/hip_runtime.h>
#include <stdint.h>

#define B_ 64
#define Q_ 900
#define T_ 100
#define C_ 256
#define INF_ 1e9f
#define QT 64       // queries per cost-kernel block
#define NQT 15      // ceil(Q_/QT)
#define TPG 25      // targets per thread (4 wave-groups x 25 = 100)
#define KSLOT 15    // ceil(Q_/64) column slots per lane (hungarian)
#define RG 4        // rows per warm-start group
#define NW 4        // waves per hung block (parallel trees)

// ---------------------------------------------------------------------------
// Wave64 min-reductions via DPP (verified on HW in round 6).
// ---------------------------------------------------------------------------
#define DPP_STEP_F(x, ctrl, rmask)                                             \
    x = fminf(x, __int_as_float(__builtin_amdgcn_update_dpp(                   \
            0x7F800000 /*+inf*/, __float_as_int(x), ctrl, rmask, 0xF, false)))
#define DPP_STEP_I(x, ctrl, rmask)                                             \
    x = min(x, __builtin_amdgcn_update_dpp(                                    \
            0x7FFFFFFF, x, ctrl, rmask, 0xF, false))

__device__ __forceinline__ float wave_min_bcast_f(float x) {
    DPP_STEP_F(x, 0x111, 0xF);   // row_shr:1
    DPP_STEP_F(x, 0x112, 0xF);   // row_shr:2
    DPP_STEP_F(x, 0x114, 0xF);   // row_shr:4
    DPP_STEP_F(x, 0x118, 0xF);   // row_shr:8
    DPP_STEP_F(x, 0x142, 0xA);   // row_bcast:15 -> rows 1,3
    DPP_STEP_F(x, 0x143, 0xC);   // row_bcast:31 -> rows 2,3
    return __int_as_float(__builtin_amdgcn_readlane(__float_as_int(x), 63));
}
__device__ __forceinline__ int wave_min_bcast_i(int x) {
    DPP_STEP_I(x, 0x111, 0xF);
    DPP_STEP_I(x, 0x112, 0xF);
    DPP_STEP_I(x, 0x114, 0xF);
    DPP_STEP_I(x, 0x118, 0xF);
    DPP_STEP_I(x, 0x142, 0xA);
    DPP_STEP_I(x, 0x143, 0xC);
    return __builtin_amdgcn_readlane(x, 63);
}

// ---------------------------------------------------------------------------
// Kernel 1: cost matrix, single-pass-per-logits-row version.
//
// Old structure split T into 5 chunks across blockIdx.y: every logits row was
// re-gathered 5x from HBM with 64B/lane granularity -> FETCH ~163MB (~2.8x the
// 59MB of logits) and a latency-bound profile (VALUBusy 12%, HBM 35%).
//
// New structure: block = (b, 64-query tile). The 64x256 logits tile is staged
// into LDS ONCE with fully-coalesced float4 loads (HBM reads logits exactly
// once = 59MB), then all 100 targets are computed from LDS.
//   - LDS row stride = 257 floats: class-gather srow[lab] has bank
//     (ql + lab) % 32 across the wave's 64 lanes -> 2 lanes/bank = free.
//   - Store lane-mapping (row = idx[9:4], c4 = idx[3:0]|idx[11:10]<<4) makes
//     ds_write banks (row + 4*(lane&15) + j) % 32 -> 2 lanes/bank = free,
//     while global reads stay coalesced (4x 256B segments per instruction).
//   - Target boxes staged as float4 (16B-aligned by type => legal b128 read).
// ---------------------------------------------------------------------------
__global__ __launch_bounds__(256) void cost_kernel(
    const float* __restrict__ logits,   // [B,Q,C]
    const float* __restrict__ pboxes,   // [B,Q,4] cxcywh
    const int*   __restrict__ tlabels,  // [B,T]
    const float* __restrict__ tboxes,   // [B,T,4] cxcywh
    float* __restrict__ cost_out,       // [B,Q,T]
    float* __restrict__ costT_out)      // [B,T,Q]
{
    const int b   = blockIdx.y;
    const int q0  = blockIdx.x * QT;
    const int tid = threadIdx.x;

    __shared__ float  s_log[QT][C_ + 1]; // 64 x 257 floats (pad kills gather conflicts)
    __shared__ float4 s_tb4[T_];         // target cxcywh (16B aligned by type)
    __shared__ int    s_lab[T_];

    // ---- stage all 100 targets once ----
    if (tid < T_) {
        s_tb4[tid] = *reinterpret_cast<const float4*>(tboxes + ((size_t)b * T_ + tid) * 4);
        s_lab[tid] = tlabels[b * T_ + tid];
    }

    // ---- stage 64x256 logits tile, coalesced, exactly once from HBM ----
    const float* __restrict__ lgb = logits + (size_t)b * Q_ * C_;
    #pragma unroll
    for (int it = 0; it < 16; ++it) {
        const int idx = it * 256 + tid;                    // 0..4095 float4 slots
        const int row = (idx >> 4) & 63;                   // bits [9:4]
        const int c4  = (idx & 15) | ((idx >> 10) << 4);   // bits [3:0] + [11:10]
        const int q   = q0 + row;
        float4 vv = make_float4(0.f, 0.f, 0.f, 0.f);
        if (q < Q_)
            vv = *reinterpret_cast<const float4*>(lgb + (size_t)q * C_ + (c4 << 2));
        float* d = &s_log[row][c4 << 2];
        d[0] = vv.x; d[1] = vv.y; d[2] = vv.z; d[3] = vv.w;
    }
    __syncthreads();

    const int ql = tid & 63;
    const int q  = q0 + ql;
    if (q >= Q_) return;                 // tail tile: no more barriers below
    const int tg = tid >> 6;             // wave id = target group

    const float4 pb = *reinterpret_cast<const float4*>(pboxes + ((size_t)b * Q_ + q) * 4);
    const float pcx = pb.x, pcy = pb.y, pw = pb.z, ph = pb.w;
    const float ax0 = pcx - 0.5f * pw, ay0 = pcy - 0.5f * ph;
    const float ax1 = pcx + 0.5f * pw, ay1 = pcy + 0.5f * ph;
    const float area_a = (ax1 - ax0) * (ay1 - ay0);   // keep reference arithmetic

    const float* __restrict__ srow = s_log[ql];
    const int tbase = tg * TPG;

    float c[TPG];
    #pragma unroll
    for (int k = 0; k < TPG; ++k) {
        const int t = tbase + k;
        const float4 tb = s_tb4[t];                                       // broadcast b128
        const float cls = -srow[s_lab[t]];                                // 2-way gather
        const float l1 = fabsf(pcx - tb.x) + fabsf(pcy - tb.y)
                       + fabsf(pw  - tb.z) + fabsf(ph  - tb.w);
        const float bx0 = tb.x - 0.5f * tb.z, by0 = tb.y - 0.5f * tb.w;
        const float bx1 = tb.x + 0.5f * tb.z, by1 = tb.y + 0.5f * tb.w;
        const float area_b = (bx1 - bx0) * (by1 - by0);
        const float ltx = fmaxf(ax0, bx0), lty = fmaxf(ay0, by0);
        const float rbx = fminf(ax1, bx1), rby = fminf(ay1, by1);
        const float wx = fmaxf(rbx - ltx, 0.0f), wy = fmaxf(rby - lty, 0.0f);
        const float inter = wx * wy;
        const float uni = area_a + area_b - inter;
        const float iou = inter / uni;
        const float ex0 = fminf(ax0, bx0), ey0 = fminf(ay0, by0);
        const float ex1 = fmaxf(ax1, bx1), ey1 = fmaxf(ay1, by1);
        const float ew = fmaxf(ex1 - ex0, 0.0f), eh = fmaxf(ey1 - ey0, 0.0f);
        const float enc = ew * eh;
        const float giou = iou - (enc - uni) / enc;
        c[k] = cls + l1 - giou;
    }

    // costT [B,T,Q]: fixed t per store, q contiguous across lanes -> coalesced
    float* __restrict__ ct = costT_out + (size_t)b * T_ * Q_ + (size_t)tbase * Q_ + q;
    #pragma unroll
    for (int k = 0; k < TPG; ++k) ct[(size_t)k * Q_] = c[k];

    // cost [B,Q,T]: 25 contiguous floats per thread; lines merge in L2
    float* __restrict__ co = cost_out + ((size_t)b * Q_ + q) * T_ + tbase;
    #pragma unroll
    for (int k = 0; k < TPG; ++k) co[k] = c[k];
}

// ---------------------------------------------------------------------------
// Kernel 2: exact Hungarian, NW=4 speculatively-parallel SAP trees per batch.
// (unchanged from the verified round-6/round-7 version)
// ---------------------------------------------------------------------------
__global__ __launch_bounds__(256) void hung_kernel(
    const float* __restrict__ costT,   // [B,T,Q]
    float* __restrict__ out_pred,      // [B,T] as float
    float* __restrict__ out_tgt)       // [B,T] as float
{
    const int b    = blockIdx.x;
    const int tid  = threadIdx.x;
    const int lane = tid & 63;
    const int wave = tid >> 6;
    const float* __restrict__ cb = costT + (size_t)b * T_ * Q_;

    __shared__ float u[128];             // [100] + pad for snapshot reads
    __shared__ float v[Q_];              // committed column duals
    __shared__ int   p[Q_];              // committed matching (col -> row)
    __shared__ int   way_priv[NW][Q_];   // per-wave predecessor arrays
    __shared__ int   ji[T_];
    __shared__ int   s_pend[T_];
    __shared__ int   col[T_];
    __shared__ int   s_mask[NW][64];     // per-wave tree column masks
    __shared__ int   s_qn, s_acc;

    // ---- init committed state ----
    for (int j = tid; j < Q_; j += 256) {
        p[j] = -1; v[j] = 0.0f; way_priv[0][j] = 0x7FFFFFFF;  // [0] = greedy scratch
    }
    if (tid >= 100 && tid < 128) u[tid] = INF_;

    // ---- warm start: u[i] = row min, ji[i] = first argmin (4 waves) ----
    for (int g = wave * RG; g < T_; g += NW * RG) {
        float rv[RG][KSLOT];
        #pragma unroll
        for (int r = 0; r < RG; ++r) {
            const float* __restrict__ row = cb + (size_t)(g + r) * Q_;
            #pragma unroll
            for (int k = 0; k < KSLOT; ++k) {
                int j = k * 64 + lane;
                rv[r][k] = (j < Q_) ? row[j] : INF_;
            }
        }
        #pragma unroll
        for (int r = 0; r < RG; ++r) {
            float m = INF_; int mj = Q_;
            #pragma unroll
            for (int k = 0; k < KSLOT; ++k) {
                int j = k * 64 + lane;
                if (rv[r][k] < m) { m = rv[r][k]; mj = j; }   // strict <: first index
            }
            const float mm = wave_min_bcast_f(m);
            const int   gj = wave_min_bcast_i((m == mm) ? mj : 0x7FFFFFFF);
            if (lane == 0) { u[g + r] = mm; ji[g + r] = gj; }
        }
    }
    __syncthreads();

    // ---- parallel greedy (wave 0): column winner = smallest suitor row ----
    if (wave == 0) {
        int t0 = lane, t1 = lane + 64;
        if (t0 < T_) atomicMin(&way_priv[0][ji[t0]], t0);
        if (t1 < T_) atomicMin(&way_priv[0][ji[t1]], t1);
        bool lose0 = false, lose1 = false;
        if (t0 < T_) {
            int j = ji[t0];
            if (way_priv[0][j] == t0) p[j] = t0; else lose0 = true;
        }
        if (t1 < T_) {
            int j = ji[t1];
            if (way_priv[0][j] == t1) p[j] = t1; else lose1 = true;
        }
        unsigned long long m0 = __ballot(lose0);
        unsigned long long m1 = __ballot(lose1);
        const int c0 = __popcll(m0);
        if (lose0) s_pend[__popcll(m0 & ((1ull << lane) - 1ull))] = lane;
        if (lose1) s_pend[c0 + __popcll(m1 & ((1ull << lane) - 1ull))] = lane + 64;
        if (lane == 0) s_qn = c0 + __popcll(m1);
    }

    // ---- super-iterations: up to NW speculative trees, disjoint-commit ----
    for (;;) {
        __syncthreads();                    // commits + queue visible
        const int qn = s_qn;
        if (qn <= 0) break;
        const int nact   = (qn < NW) ? qn : NW;
        const bool active = (wave < nact);
        const int  isrc   = active ? s_pend[wave] : -1;

        // committed snapshots (stable this super-iteration)
        const float u_lo = u[lane];
        const float u_hi = u[64 + lane];
        float vreg[KSLOT];
        #pragma unroll
        for (int k = 0; k < KSLOT; ++k) {
            int j = k * 64 + lane;
            vreg[k] = (j < Q_) ? v[j] : 0.0f;
        }

        unsigned int used = 0;
        float vadd[KSLOT], minv[KSLOT];
        float uisrc_acc = 0.0f;
        int jfin = Q_;

        if (active) {
            int* __restrict__ wayw = way_priv[wave];
            #pragma unroll
            for (int k = 0; k < KSLOT; ++k) { minv[k] = INF_; vadd[k] = 0.0f; }
            int j0 = Q_;
            uisrc_acc = u[isrc];
            float uicur = uisrc_acc;

            float pre[KSLOT];
            {
                const float* __restrict__ row = cb + (size_t)isrc * Q_;
                #pragma unroll
                for (int k = 0; k < KSLOT; ++k) {
                    int j = k * 64 + lane;
                    pre[k] = (j < Q_) ? row[j] : INF_;
                }
            }

            while (true) {
                float best = INF_; int bj = Q_;
                #pragma unroll
                for (int k = 0; k < KSLOT; ++k) {
                    int j = k * 64 + lane;
                    if (j < Q_ && !((used >> k) & 1u)) {
                        float cur = pre[k] - uicur - vreg[k];
                        if (cur < minv[k]) { minv[k] = cur; wayw[j] = j0; }
                        float mm = minv[k];
                        if (mm < best) { best = mm; bj = j; }
                    }
                }
                const float delta = wave_min_bcast_f(best);
                const int   j1    = wave_min_bcast_i((best == delta) ? bj : 0x7FFFFFFF);
                const int   inext = p[j1];          // committed (stable)

                // speculative prefetch of next row
                {
                    int ipre = (inext < 0) ? 0 : inext;
                    const float* __restrict__ row = cb + (size_t)ipre * Q_;
                    #pragma unroll
                    for (int k = 0; k < KSLOT; ++k) {
                        int j = k * 64 + lane;
                        pre[k] = (j < Q_) ? row[j] : INF_;
                    }
                }

                // dual updates (j1 counted FREE here, as reference/r6)
                uisrc_acc += delta;
                #pragma unroll
                for (int k = 0; k < KSLOT; ++k) {
                    int j = k * 64 + lane;
                    if (j < Q_) {
                        if ((used >> k) & 1u) vadd[k] += delta;
                        else                  minv[k] -= delta;
                    }
                }

                if (inext < 0) { jfin = j1; break; }

                if (lane == (j1 & 63)) used |= 1u << (j1 >> 6);
                {
                    const int si = __builtin_amdgcn_readfirstlane(inext);
                    const float tsel = (si < 64) ? u_lo : u_hi;
                    uicur = __int_as_float(
                        __builtin_amdgcn_readlane(__float_as_int(tsel), si & 63));
                }
                j0 = j1;
            }
        }

        // publish tree column mask (used cols + final col)
        {
            int msk = active ? (int)used : 0;
            if (active && lane == (jfin & 63)) msk |= 1 << (jfin >> 6);
            s_mask[wave][lane] = msk;
        }
        __syncthreads();

        // acceptance: greedy prefix in pend order, pairwise disjoint (wave 0)
        if (wave == 0) {
            int acc = 1;
            for (int bb = 1; bb < nact; ++bb) {
                int mb = s_mask[bb][lane];
                bool ok = true;
                for (int aa = 0; aa < bb; ++aa) {
                    if ((acc >> aa) & 1) {
                        bool hit = (s_mask[aa][lane] & mb) != 0;
                        if (__ballot(hit) != 0ull) ok = false;
                    }
                }
                if (ok) acc |= 1 << bb;
            }
            if (lane == 0) s_acc = acc;
        }
        __syncthreads();

        // commit accepted trees (disjoint => parallel-safe)
        if (active && ((s_acc >> wave) & 1)) {
            #pragma unroll
            for (int k = 0; k < KSLOT; ++k) {
                int j = k * 64 + lane;
                if (j < Q_ && ((used >> k) & 1u)) {
                    int r = p[j];                  // row matched to j (pre-augment)
                    u[r] = u[r] + vadd[k];
                    v[j] = v[j] - vadd[k];
                }
            }
            if (lane == 0) {
                u[isrc] = uisrc_acc;
                int jj = jfin;
                int* __restrict__ wayw = way_priv[wave];
                while (true) {
                    int jp = wayw[jj];
                    if (jp == Q_) { p[jj] = isrc; break; }
                    p[jj] = p[jp];
                    jj = jp;
                }
            }
        }
        __syncthreads();

        // rebuild queue (rejected keep order, go to front)
        if (tid == 0) {
            int acc = s_acc;
            int tmp[NW]; int nrej = 0;
            for (int w = 0; w < nact; ++w)
                if (!((acc >> w) & 1)) tmp[nrej++] = s_pend[w];
            for (int i = 0; i < nrej; ++i) s_pend[i] = tmp[i];
            for (int i = nact; i < qn; ++i) s_pend[nrej + i - nact] = s_pend[i];
            s_qn = qn - nact + nrej;
        }
    }

    // ---- outputs: col[t] = assigned query; rank-sort ascending by query ----
    for (int j = tid; j < Q_; j += 256) {
        int r = p[j];
        if (r >= 0) col[r] = j;
    }
    __syncthreads();
    if (tid < T_) {
        int cj = col[tid];
        int rank = 0;
        for (int t2 = 0; t2 < T_; ++t2) rank += (col[t2] < cj) ? 1 : 0;
        out_pred[b * T_ + rank] = (float)cj;
        out_tgt [b * T_ + rank] = (float)tid;
    }
}

extern "C" void kernel_launch(void* const* d_in, const int* in_sizes, int n_in,
                              void* d_out, int out_size, void* d_ws, size_t ws_size,
                              hipStream_t stream) {
    const float* logits  = (const float*)d_in[0];   // [B,Q,C]
    const float* pboxes  = (const float*)d_in[1];   // [B,Q,4]
    const int*   tlabels = (const int*)d_in[2];     // [B,T]
    const float* tboxes  = (const float*)d_in[3];   // [B,T,4]

    float* out      = (float*)d_out;
    float* cost     = out;                                   // [B,Q,T]
    float* out_pred = out + (size_t)B_ * Q_ * T_;            // [B,T]
    float* out_tgt  = out_pred + (size_t)B_ * T_;            // [B,T]

    float* costT = (float*)d_ws;  // [B,T,Q]; ws >= 23 MB proven

    dim3 gridc(NQT, B_);
    cost_kernel<<<gridc, 256, 0, stream>>>(logits, pboxes, tlabels, tboxes, cost, costT);
    hung_kernel<<<B_, 256, 0, stream>>>(costT, out_pred, out_tgt);
}

// Round 4
// 166.543 us; speedup vs baseline: 1.1531x; 1.0032x over previous
//
#include <hip/hip_runtime.h>
#include <stdint.h>

#define B_ 64
#define Q_ 900
#define T_ 100
#define C_ 256
#define INF_ 1e9f
#define QT 32       // queries per cost-kernel block (32.9KB tile -> 4 blocks/CU)
#define NQB 29      // ceil(Q_/QT)
#define NG 8        // target groups per block (tid>>5)
#define TPG 13      // targets per group (last group has 9)
#define KSLOT 15    // ceil(Q_/64) column slots per lane (hungarian)
#define RG 4        // rows per warm-start group
#define NW 4        // waves per hung block (parallel trees)

// ---------------------------------------------------------------------------
// Wave64 min-reductions via DPP (verified on HW in round 6).
// ---------------------------------------------------------------------------
#define DPP_STEP_F(x, ctrl, rmask)                                             \
    x = fminf(x, __int_as_float(__builtin_amdgcn_update_dpp(                   \
            0x7F800000 /*+inf*/, __float_as_int(x), ctrl, rmask, 0xF, false)))
#define DPP_STEP_I(x, ctrl, rmask)                                             \
    x = min(x, __builtin_amdgcn_update_dpp(                                    \
            0x7FFFFFFF, x, ctrl, rmask, 0xF, false))

__device__ __forceinline__ float wave_min_bcast_f(float x) {
    DPP_STEP_F(x, 0x111, 0xF);   // row_shr:1
    DPP_STEP_F(x, 0x112, 0xF);   // row_shr:2
    DPP_STEP_F(x, 0x114, 0xF);   // row_shr:4
    DPP_STEP_F(x, 0x118, 0xF);   // row_shr:8
    DPP_STEP_F(x, 0x142, 0xA);   // row_bcast:15 -> rows 1,3
    DPP_STEP_F(x, 0x143, 0xC);   // row_bcast:31 -> rows 2,3
    return __int_as_float(__builtin_amdgcn_readlane(__float_as_int(x), 63));
}
__device__ __forceinline__ int wave_min_bcast_i(int x) {
    DPP_STEP_I(x, 0x111, 0xF);
    DPP_STEP_I(x, 0x112, 0xF);
    DPP_STEP_I(x, 0x114, 0xF);
    DPP_STEP_I(x, 0x118, 0xF);
    DPP_STEP_I(x, 0x142, 0xA);
    DPP_STEP_I(x, 0x143, 0xC);
    return __builtin_amdgcn_readlane(x, 63);
}

// ---------------------------------------------------------------------------
// Kernel 1: cost matrix. Round-3 version (QT=64, 68KB LDS) was latency-bound:
// Occupancy 15% (2 blocks/CU), VALUBusy 21%, HBM 21% -- all low. This version
// halves the tile (QT=32, ~35KB LDS) -> 4 blocks/CU = 16 waves/CU, and grows
// the grid 960 -> 1856 blocks. Same arithmetic, same one-pass HBM traffic.
//   - s_log stride 257: gather bank = (r + lab) % 32, r in [0,32) distinct
//     per half-wave -> conflict-free; 2 labels/wave64 = free 2-way.
//   - Staging: wave = one 1KB logits row -> perfectly coalesced; LDS writes
//     contiguous within a row (natural full-bandwidth pattern).
// ---------------------------------------------------------------------------
__global__ __launch_bounds__(256) void cost_kernel(
    const float* __restrict__ logits,   // [B,Q,C]
    const float* __restrict__ pboxes,   // [B,Q,4] cxcywh
    const int*   __restrict__ tlabels,  // [B,T]
    const float* __restrict__ tboxes,   // [B,T,4] cxcywh
    float* __restrict__ cost_out,       // [B,Q,T]
    float* __restrict__ costT_out)      // [B,T,Q]
{
    const int b   = blockIdx.y;
    const int q0  = blockIdx.x * QT;
    const int tid = threadIdx.x;

    __shared__ float  s_log[QT][C_ + 1]; // 32 x 257 floats = 32.9KB
    __shared__ float4 s_tb4[T_];         // target cxcywh (16B aligned by type)
    __shared__ int    s_lab[T_];

    // ---- stage all 100 targets once ----
    if (tid < T_) {
        s_tb4[tid] = *reinterpret_cast<const float4*>(tboxes + ((size_t)b * T_ + tid) * 4);
        s_lab[tid] = tlabels[b * T_ + tid];
    }

    // ---- stage 32x256 logits tile, coalesced, once from HBM ----
    const float* __restrict__ lgb = logits + (size_t)b * Q_ * C_;
    #pragma unroll
    for (int it = 0; it < 8; ++it) {
        const int idx = it * 256 + tid;        // 0..2047 float4 slots
        const int row = idx >> 6;              // 0..31 (wave covers one row)
        const int c4  = idx & 63;              // float4 column
        const int q   = q0 + row;
        float4 vv = make_float4(0.f, 0.f, 0.f, 0.f);
        if (q < Q_)
            vv = *reinterpret_cast<const float4*>(lgb + (size_t)q * C_ + (c4 << 2));
        float* d = &s_log[row][c4 << 2];
        d[0] = vv.x; d[1] = vv.y; d[2] = vv.z; d[3] = vv.w;
    }
    __syncthreads();

    const int qr = tid & 31;
    const int q  = q0 + qr;
    if (q >= Q_) return;                 // tail tile: no more barriers below
    const int g  = tid >> 5;             // target group 0..7

    const float4 pb = *reinterpret_cast<const float4*>(pboxes + ((size_t)b * Q_ + q) * 4);
    const float pcx = pb.x, pcy = pb.y, pw = pb.z, ph = pb.w;
    const float ax0 = pcx - 0.5f * pw, ay0 = pcy - 0.5f * ph;
    const float ax1 = pcx + 0.5f * pw, ay1 = pcy + 0.5f * ph;
    const float area_a = (ax1 - ax0) * (ay1 - ay0);   // keep reference arithmetic

    const float* __restrict__ srow = s_log[qr];
    const int tbase = g * TPG;                 // 0,13,...,91
    const int tcnt  = (T_ - tbase < TPG) ? (T_ - tbase) : TPG;   // 13 or 9

    float c[TPG];
    #pragma unroll
    for (int k = 0; k < TPG; ++k) {
        const int t = tbase + ((k < tcnt) ? k : 0);               // clamp (dup work, no OOB)
        const float4 tb = s_tb4[t];                               // broadcast b128
        const float cls = -srow[s_lab[t]];                        // conflict-free gather
        const float l1 = fabsf(pcx - tb.x) + fabsf(pcy - tb.y)
                       + fabsf(pw  - tb.z) + fabsf(ph  - tb.w);
        const float bx0 = tb.x - 0.5f * tb.z, by0 = tb.y - 0.5f * tb.w;
        const float bx1 = tb.x + 0.5f * tb.z, by1 = tb.y + 0.5f * tb.w;
        const float area_b = (bx1 - bx0) * (by1 - by0);
        const float ltx = fmaxf(ax0, bx0), lty = fmaxf(ay0, by0);
        const float rbx = fminf(ax1, bx1), rby = fminf(ay1, by1);
        const float wx = fmaxf(rbx - ltx, 0.0f), wy = fmaxf(rby - lty, 0.0f);
        const float inter = wx * wy;
        const float uni = area_a + area_b - inter;
        const float iou = inter / uni;
        const float ex0 = fminf(ax0, bx0), ey0 = fminf(ay0, by0);
        const float ex1 = fmaxf(ax1, bx1), ey1 = fmaxf(ay1, by1);
        const float ew = fmaxf(ex1 - ex0, 0.0f), eh = fmaxf(ey1 - ey0, 0.0f);
        const float enc = ew * eh;
        const float giou = iou - (enc - uni) / enc;
        c[k] = cls + l1 - giou;
    }

    // costT [B,T,Q]: fixed t per store, q contiguous across half-wave -> coalesced
    float* __restrict__ ct = costT_out + (size_t)b * T_ * Q_ + (size_t)tbase * Q_ + q;
    #pragma unroll
    for (int k = 0; k < TPG; ++k)
        if (k < tcnt) ct[(size_t)k * Q_] = c[k];

    // cost [B,Q,T]: 13 contiguous floats per thread; lines merge in L2
    float* __restrict__ co = cost_out + ((size_t)b * Q_ + q) * T_ + tbase;
    #pragma unroll
    for (int k = 0; k < TPG; ++k)
        if (k < tcnt) co[k] = c[k];
}

// ---------------------------------------------------------------------------
// Kernel 2: exact Hungarian, NW=4 speculatively-parallel SAP trees per batch.
// (unchanged from the verified round-6/round-7 version)
// ---------------------------------------------------------------------------
__global__ __launch_bounds__(256) void hung_kernel(
    const float* __restrict__ costT,   // [B,T,Q]
    float* __restrict__ out_pred,      // [B,T] as float
    float* __restrict__ out_tgt)       // [B,T] as float
{
    const int b    = blockIdx.x;
    const int tid  = threadIdx.x;
    const int lane = tid & 63;
    const int wave = tid >> 6;
    const float* __restrict__ cb = costT + (size_t)b * T_ * Q_;

    __shared__ float u[128];             // [100] + pad for snapshot reads
    __shared__ float v[Q_];              // committed column duals
    __shared__ int   p[Q_];              // committed matching (col -> row)
    __shared__ int   way_priv[NW][Q_];   // per-wave predecessor arrays
    __shared__ int   ji[T_];
    __shared__ int   s_pend[T_];
    __shared__ int   col[T_];
    __shared__ int   s_mask[NW][64];     // per-wave tree column masks
    __shared__ int   s_qn, s_acc;

    // ---- init committed state ----
    for (int j = tid; j < Q_; j += 256) {
        p[j] = -1; v[j] = 0.0f; way_priv[0][j] = 0x7FFFFFFF;  // [0] = greedy scratch
    }
    if (tid >= 100 && tid < 128) u[tid] = INF_;

    // ---- warm start: u[i] = row min, ji[i] = first argmin (4 waves) ----
    for (int g = wave * RG; g < T_; g += NW * RG) {
        float rv[RG][KSLOT];
        #pragma unroll
        for (int r = 0; r < RG; ++r) {
            const float* __restrict__ row = cb + (size_t)(g + r) * Q_;
            #pragma unroll
            for (int k = 0; k < KSLOT; ++k) {
                int j = k * 64 + lane;
                rv[r][k] = (j < Q_) ? row[j] : INF_;
            }
        }
        #pragma unroll
        for (int r = 0; r < RG; ++r) {
            float m = INF_; int mj = Q_;
            #pragma unroll
            for (int k = 0; k < KSLOT; ++k) {
                int j = k * 64 + lane;
                if (rv[r][k] < m) { m = rv[r][k]; mj = j; }   // strict <: first index
            }
            const float mm = wave_min_bcast_f(m);
            const int   gj = wave_min_bcast_i((m == mm) ? mj : 0x7FFFFFFF);
            if (lane == 0) { u[g + r] = mm; ji[g + r] = gj; }
        }
    }
    __syncthreads();

    // ---- parallel greedy (wave 0): column winner = smallest suitor row ----
    if (wave == 0) {
        int t0 = lane, t1 = lane + 64;
        if (t0 < T_) atomicMin(&way_priv[0][ji[t0]], t0);
        if (t1 < T_) atomicMin(&way_priv[0][ji[t1]], t1);
        bool lose0 = false, lose1 = false;
        if (t0 < T_) {
            int j = ji[t0];
            if (way_priv[0][j] == t0) p[j] = t0; else lose0 = true;
        }
        if (t1 < T_) {
            int j = ji[t1];
            if (way_priv[0][j] == t1) p[j] = t1; else lose1 = true;
        }
        unsigned long long m0 = __ballot(lose0);
        unsigned long long m1 = __ballot(lose1);
        const int c0 = __popcll(m0);
        if (lose0) s_pend[__popcll(m0 & ((1ull << lane) - 1ull))] = lane;
        if (lose1) s_pend[c0 + __popcll(m1 & ((1ull << lane) - 1ull))] = lane + 64;
        if (lane == 0) s_qn = c0 + __popcll(m1);
    }

    // ---- super-iterations: up to NW speculative trees, disjoint-commit ----
    for (;;) {
        __syncthreads();                    // commits + queue visible
        const int qn = s_qn;
        if (qn <= 0) break;
        const int nact   = (qn < NW) ? qn : NW;
        const bool active = (wave < nact);
        const int  isrc   = active ? s_pend[wave] : -1;

        // committed snapshots (stable this super-iteration)
        const float u_lo = u[lane];
        const float u_hi = u[64 + lane];
        float vreg[KSLOT];
        #pragma unroll
        for (int k = 0; k < KSLOT; ++k) {
            int j = k * 64 + lane;
            vreg[k] = (j < Q_) ? v[j] : 0.0f;
        }

        unsigned int used = 0;
        float vadd[KSLOT], minv[KSLOT];
        float uisrc_acc = 0.0f;
        int jfin = Q_;

        if (active) {
            int* __restrict__ wayw = way_priv[wave];
            #pragma unroll
            for (int k = 0; k < KSLOT; ++k) { minv[k] = INF_; vadd[k] = 0.0f; }
            int j0 = Q_;
            uisrc_acc = u[isrc];
            float uicur = uisrc_acc;

            float pre[KSLOT];
            {
                const float* __restrict__ row = cb + (size_t)isrc * Q_;
                #pragma unroll
                for (int k = 0; k < KSLOT; ++k) {
                    int j = k * 64 + lane;
                    pre[k] = (j < Q_) ? row[j] : INF_;
                }
            }

            while (true) {
                float best = INF_; int bj = Q_;
                #pragma unroll
                for (int k = 0; k < KSLOT; ++k) {
                    int j = k * 64 + lane;
                    if (j < Q_ && !((used >> k) & 1u)) {
                        float cur = pre[k] - uicur - vreg[k];
                        if (cur < minv[k]) { minv[k] = cur; wayw[j] = j0; }
                        float mm = minv[k];
                        if (mm < best) { best = mm; bj = j; }
                    }
                }
                const float delta = wave_min_bcast_f(best);
                const int   j1    = wave_min_bcast_i((best == delta) ? bj : 0x7FFFFFFF);
                const int   inext = p[j1];          // committed (stable)

                // speculative prefetch of next row
                {
                    int ipre = (inext < 0) ? 0 : inext;
                    const float* __restrict__ row = cb + (size_t)ipre * Q_;
                    #pragma unroll
                    for (int k = 0; k < KSLOT; ++k) {
                        int j = k * 64 + lane;
                        pre[k] = (j < Q_) ? row[j] : INF_;
                    }
                }

                // dual updates (j1 counted FREE here, as reference/r6)
                uisrc_acc += delta;
                #pragma unroll
                for (int k = 0; k < KSLOT; ++k) {
                    int j = k * 64 + lane;
                    if (j < Q_) {
                        if ((used >> k) & 1u) vadd[k] += delta;
                        else                  minv[k] -= delta;
                    }
                }

                if (inext < 0) { jfin = j1; break; }

                if (lane == (j1 & 63)) used |= 1u << (j1 >> 6);
                {
                    const int si = __builtin_amdgcn_readfirstlane(inext);
                    const float tsel = (si < 64) ? u_lo : u_hi;
                    uicur = __int_as_float(
                        __builtin_amdgcn_readlane(__float_as_int(tsel), si & 63));
                }
                j0 = j1;
            }
        }

        // publish tree column mask (used cols + final col)
        {
            int msk = active ? (int)used : 0;
            if (active && lane == (jfin & 63)) msk |= 1 << (jfin >> 6);
            s_mask[wave][lane] = msk;
        }
        __syncthreads();

        // acceptance: greedy prefix in pend order, pairwise disjoint (wave 0)
        if (wave == 0) {
            int acc = 1;
            for (int bb = 1; bb < nact; ++bb) {
                int mb = s_mask[bb][lane];
                bool ok = true;
                for (int aa = 0; aa < bb; ++aa) {
                    if ((acc >> aa) & 1) {
                        bool hit = (s_mask[aa][lane] & mb) != 0;
                        if (__ballot(hit) != 0ull) ok = false;
                    }
                }
                if (ok) acc |= 1 << bb;
            }
            if (lane == 0) s_acc = acc;
        }
        __syncthreads();

        // commit accepted trees (disjoint => parallel-safe)
        if (active && ((s_acc >> wave) & 1)) {
            #pragma unroll
            for (int k = 0; k < KSLOT; ++k) {
                int j = k * 64 + lane;
                if (j < Q_ && ((used >> k) & 1u)) {
                    int r = p[j];                  // row matched to j (pre-augment)
                    u[r] = u[r] + vadd[k];
                    v[j] = v[j] - vadd[k];
                }
            }
            if (lane == 0) {
                u[isrc] = uisrc_acc;
                int jj = jfin;
                int* __restrict__ wayw = way_priv[wave];
                while (true) {
                    int jp = wayw[jj];
                    if (jp == Q_) { p[jj] = isrc; break; }
                    p[jj] = p[jp];
                    jj = jp;
                }
            }
        }
        __syncthreads();

        // rebuild queue (rejected keep order, go to front)
        if (tid == 0) {
            int acc = s_acc;
            int tmp[NW]; int nrej = 0;
            for (int w = 0; w < nact; ++w)
                if (!((acc >> w) & 1)) tmp[nrej++] = s_pend[w];
            for (int i = 0; i < nrej; ++i) s_pend[i] = tmp[i];
            for (int i = nact; i < qn; ++i) s_pend[nrej + i - nact] = s_pend[i];
            s_qn = qn - nact + nrej;
        }
    }

    // ---- outputs: col[t] = assigned query; rank-sort ascending by query ----
    for (int j = tid; j < Q_; j += 256) {
        int r = p[j];
        if (r >= 0) col[r] = j;
    }
    __syncthreads();
    if (tid < T_) {
        int cj = col[tid];
        int rank = 0;
        for (int t2 = 0; t2 < T_; ++t2) rank += (col[t2] < cj) ? 1 : 0;
        out_pred[b * T_ + rank] = (float)cj;
        out_tgt [b * T_ + rank] = (float)tid;
    }
}

extern "C" void kernel_launch(void* const* d_in, const int* in_sizes, int n_in,
                              void* d_out, int out_size, void* d_ws, size_t ws_size,
                              hipStream_t stream) {
    const float* logits  = (const float*)d_in[0];   // [B,Q,C]
    const float* pboxes  = (const float*)d_in[1];   // [B,Q,4]
    const int*   tlabels = (const int*)d_in[2];     // [B,T]
    const float* tboxes  = (const float*)d_in[3];   // [B,T,4]

    float* out      = (float*)d_out;
    float* cost     = out;                                   // [B,Q,T]
    float* out_pred = out + (size_t)B_ * Q_ * T_;            // [B,T]
    float* out_tgt  = out_pred + (size_t)B_ * T_;            // [B,T]

    float* costT = (float*)d_ws;  // [B,T,Q]; ws >= 23 MB proven

    dim3 gridc(NQB, B_);
    cost_kernel<<<gridc, 256, 0, stream>>>(logits, pboxes, tlabels, tboxes, cost, costT);
    hung_kernel<<<B_, 256, 0, stream>>>(costT, out_pred, out_tgt);
}

// Round 5
// 161.903 us; speedup vs baseline: 1.1861x; 1.0287x over previous
//
#include <hip/hip_runtime.h>
#include <stdint.h>

#define B_ 64
#define Q_ 900
#define T_ 100
#define C_ 256
#define INF_ 1e9f
#define QT 32       // queries per cost-kernel block
#define NQB 29      // ceil(Q_/QT)
#define NG 8        // target groups per block (tid>>5)
#define TPG 13      // targets per group (last group has 9)
#define SC 101      // s_c stride: bank=(5*qr+t)%32, 5 coprime 32 -> conflict-free
#define KSLOT 15    // ceil(Q_/64) column slots per lane (hungarian)
#define RG 4        // rows per warm-start group
#define NW 4        // waves per hung block (parallel trees)

// ---------------------------------------------------------------------------
// Wave64 min-reductions via DPP (verified on HW in round 6).
// ---------------------------------------------------------------------------
#define DPP_STEP_F(x, ctrl, rmask)                                             \
    x = fminf(x, __int_as_float(__builtin_amdgcn_update_dpp(                   \
            0x7F800000 /*+inf*/, __float_as_int(x), ctrl, rmask, 0xF, false)))
#define DPP_STEP_I(x, ctrl, rmask)                                             \
    x = min(x, __builtin_amdgcn_update_dpp(                                    \
            0x7FFFFFFF, x, ctrl, rmask, 0xF, false))

__device__ __forceinline__ float wave_min_bcast_f(float x) {
    DPP_STEP_F(x, 0x111, 0xF);   // row_shr:1
    DPP_STEP_F(x, 0x112, 0xF);   // row_shr:2
    DPP_STEP_F(x, 0x114, 0xF);   // row_shr:4
    DPP_STEP_F(x, 0x118, 0xF);   // row_shr:8
    DPP_STEP_F(x, 0x142, 0xA);   // row_bcast:15 -> rows 1,3
    DPP_STEP_F(x, 0x143, 0xC);   // row_bcast:31 -> rows 2,3
    return __int_as_float(__builtin_amdgcn_readlane(__float_as_int(x), 63));
}
__device__ __forceinline__ int wave_min_bcast_i(int x) {
    DPP_STEP_I(x, 0x111, 0xF);
    DPP_STEP_I(x, 0x112, 0xF);
    DPP_STEP_I(x, 0x114, 0xF);
    DPP_STEP_I(x, 0x118, 0xF);
    DPP_STEP_I(x, 0x142, 0xA);
    DPP_STEP_I(x, 0x143, 0xC);
    return __builtin_amdgcn_readlane(x, 63);
}

// ---------------------------------------------------------------------------
// Kernel 1: cost matrix.
// r4 post-mortem: occupancy 15->30% left dur unchanged => NOT latency-bound.
// Hypothesis: the [B,Q,T] cost store (4B/lane at 400B stride = 64 cachelines
// per wave-store, 5.76M line-touches total) saturates the TA/L2 transaction
// path. Fix: transpose through LDS (s_c[32][101], conflict-free banks) and
// stream the 32x100 tile -- contiguous in cost -- with lane-contiguous
// stores (line-touches/block 3328 -> ~200).
// Also restores r3's staging lane-map (<=2-way ds_write banks; r4's simple
// map was 8-way, 1.43M conflict cycles).
// ---------------------------------------------------------------------------
__global__ __launch_bounds__(256) void cost_kernel(
    const float* __restrict__ logits,   // [B,Q,C]
    const float* __restrict__ pboxes,   // [B,Q,4] cxcywh
    const int*   __restrict__ tlabels,  // [B,T]
    const float* __restrict__ tboxes,   // [B,T,4] cxcywh
    float* __restrict__ cost_out,       // [B,Q,T]
    float* __restrict__ costT_out)      // [B,T,Q]
{
    const int b   = blockIdx.y;
    const int q0  = blockIdx.x * QT;
    const int tid = threadIdx.x;

    __shared__ float  s_log[QT][C_ + 1]; // 32 x 257 floats = 32.9KB
    __shared__ float  s_c[QT][SC];       // transpose buffer, 12.9KB
    __shared__ float4 s_tb4[T_];         // target cxcywh (16B aligned by type)
    __shared__ int    s_lab[T_];

    // ---- stage all 100 targets once ----
    if (tid < T_) {
        s_tb4[tid] = *reinterpret_cast<const float4*>(tboxes + ((size_t)b * T_ + tid) * 4);
        s_lab[tid] = tlabels[b * T_ + tid];
    }

    // ---- stage 32x256 logits tile, coalesced, once from HBM ----
    // lane map: row=idx[8:4], c4=idx[3:0]|idx[10:9]<<4
    //   global: 4 x 256B segments per wave (coalesced)
    //   LDS: bank=(row+4*c4[3:0]+j)%32 -> <=2 lanes/bank (free)
    const float* __restrict__ lgb = logits + (size_t)b * Q_ * C_;
    #pragma unroll
    for (int it = 0; it < 8; ++it) {
        const int idx = it * 256 + tid;                  // 0..2047 float4 slots
        const int row = (idx >> 4) & 31;                 // idx[8:4]
        const int c4  = (idx & 15) | ((idx >> 9) << 4);  // idx[3:0] | idx[10:9]<<4
        const int q   = q0 + row;
        float4 vv = make_float4(0.f, 0.f, 0.f, 0.f);
        if (q < Q_)
            vv = *reinterpret_cast<const float4*>(lgb + (size_t)q * C_ + (c4 << 2));
        float* d = &s_log[row][c4 << 2];
        d[0] = vv.x; d[1] = vv.y; d[2] = vv.z; d[3] = vv.w;
    }
    __syncthreads();

    const int qr  = tid & 31;
    const int q   = q0 + qr;
    const bool qok = (q < Q_);
    const int qc  = qok ? q : (Q_ - 1);    // clamped for safe (discarded) loads
    const int g   = tid >> 5;              // target group 0..7

    const float4 pb = *reinterpret_cast<const float4*>(pboxes + ((size_t)b * Q_ + qc) * 4);
    const float pcx = pb.x, pcy = pb.y, pw = pb.z, ph = pb.w;
    const float ax0 = pcx - 0.5f * pw, ay0 = pcy - 0.5f * ph;
    const float ax1 = pcx + 0.5f * pw, ay1 = pcy + 0.5f * ph;
    const float area_a = (ax1 - ax0) * (ay1 - ay0);   // keep reference arithmetic

    const float* __restrict__ srow = s_log[qr];
    const int tbase = g * TPG;                 // 0,13,...,91
    const int tcnt  = (T_ - tbase < TPG) ? (T_ - tbase) : TPG;   // 13 or 9

    float c[TPG];
    #pragma unroll
    for (int k = 0; k < TPG; ++k) {
        const int t = tbase + ((k < tcnt) ? k : 0);               // clamp (dup work, no OOB)
        const float4 tb = s_tb4[t];                               // broadcast b128
        const float cls = -srow[s_lab[t]];                        // conflict-free gather
        const float l1 = fabsf(pcx - tb.x) + fabsf(pcy - tb.y)
                       + fabsf(pw  - tb.z) + fabsf(ph  - tb.w);
        const float bx0 = tb.x - 0.5f * tb.z, by0 = tb.y - 0.5f * tb.w;
        const float bx1 = tb.x + 0.5f * tb.z, by1 = tb.y + 0.5f * tb.w;
        const float area_b = (bx1 - bx0) * (by1 - by0);
        const float ltx = fmaxf(ax0, bx0), lty = fmaxf(ay0, by0);
        const float rbx = fminf(ax1, bx1), rby = fminf(ay1, by1);
        const float wx = fmaxf(rbx - ltx, 0.0f), wy = fmaxf(rby - lty, 0.0f);
        const float inter = wx * wy;
        const float uni = area_a + area_b - inter;
        const float iou = inter / uni;
        const float ex0 = fminf(ax0, bx0), ey0 = fminf(ay0, by0);
        const float ex1 = fmaxf(ax1, bx1), ey1 = fmaxf(ay1, by1);
        const float ew = fmaxf(ex1 - ex0, 0.0f), eh = fmaxf(ey1 - ey0, 0.0f);
        const float enc = ew * eh;
        const float giou = iou - (enc - uni) / enc;
        c[k] = cls + l1 - giou;
    }

    // costT [B,T,Q]: fixed t per store, q contiguous across half-wave -> coalesced
    if (qok) {
        float* __restrict__ ct = costT_out + (size_t)b * T_ * Q_ + (size_t)tbase * Q_ + q;
        #pragma unroll
        for (int k = 0; k < TPG; ++k)
            if (k < tcnt) ct[(size_t)k * Q_] = c[k];

        // transpose into LDS: bank=(5*qr+t)%32, bijective per half-wave -> free
        #pragma unroll
        for (int k = 0; k < TPG; ++k)
            if (k < tcnt) s_c[qr][tbase + k] = c[k];
    }
    __syncthreads();

    // cost [B,Q,T]: the block's 32x100 tile is CONTIGUOUS (row stride = T_).
    // Lane-contiguous b32 stores: each wave-store spans 256B = 2 lines.
    const int nrows = (Q_ - q0 < QT) ? (Q_ - q0) : QT;
    const int ntot  = nrows * T_;
    float* __restrict__ tile = cost_out + ((size_t)b * Q_ + q0) * T_;
    for (int idx = tid; idx < ntot; idx += 256) {
        const int r = idx / T_;
        const int t = idx - r * T_;
        tile[idx] = s_c[r][t];
    }
}

// ---------------------------------------------------------------------------
// Kernel 2: exact Hungarian, NW=4 speculatively-parallel SAP trees per batch.
// (unchanged from the verified round-6/round-7 version)
// ---------------------------------------------------------------------------
__global__ __launch_bounds__(256) void hung_kernel(
    const float* __restrict__ costT,   // [B,T,Q]
    float* __restrict__ out_pred,      // [B,T] as float
    float* __restrict__ out_tgt)       // [B,T] as float
{
    const int b    = blockIdx.x;
    const int tid  = threadIdx.x;
    const int lane = tid & 63;
    const int wave = tid >> 6;
    const float* __restrict__ cb = costT + (size_t)b * T_ * Q_;

    __shared__ float u[128];             // [100] + pad for snapshot reads
    __shared__ float v[Q_];              // committed column duals
    __shared__ int   p[Q_];              // committed matching (col -> row)
    __shared__ int   way_priv[NW][Q_];   // per-wave predecessor arrays
    __shared__ int   ji[T_];
    __shared__ int   s_pend[T_];
    __shared__ int   col[T_];
    __shared__ int   s_mask[NW][64];     // per-wave tree column masks
    __shared__ int   s_qn, s_acc;

    // ---- init committed state ----
    for (int j = tid; j < Q_; j += 256) {
        p[j] = -1; v[j] = 0.0f; way_priv[0][j] = 0x7FFFFFFF;  // [0] = greedy scratch
    }
    if (tid >= 100 && tid < 128) u[tid] = INF_;

    // ---- warm start: u[i] = row min, ji[i] = first argmin (4 waves) ----
    for (int g = wave * RG; g < T_; g += NW * RG) {
        float rv[RG][KSLOT];
        #pragma unroll
        for (int r = 0; r < RG; ++r) {
            const float* __restrict__ row = cb + (size_t)(g + r) * Q_;
            #pragma unroll
            for (int k = 0; k < KSLOT; ++k) {
                int j = k * 64 + lane;
                rv[r][k] = (j < Q_) ? row[j] : INF_;
            }
        }
        #pragma unroll
        for (int r = 0; r < RG; ++r) {
            float m = INF_; int mj = Q_;
            #pragma unroll
            for (int k = 0; k < KSLOT; ++k) {
                int j = k * 64 + lane;
                if (rv[r][k] < m) { m = rv[r][k]; mj = j; }   // strict <: first index
            }
            const float mm = wave_min_bcast_f(m);
            const int   gj = wave_min_bcast_i((m == mm) ? mj : 0x7FFFFFFF);
            if (lane == 0) { u[g + r] = mm; ji[g + r] = gj; }
        }
    }
    __syncthreads();

    // ---- parallel greedy (wave 0): column winner = smallest suitor row ----
    if (wave == 0) {
        int t0 = lane, t1 = lane + 64;
        if (t0 < T_) atomicMin(&way_priv[0][ji[t0]], t0);
        if (t1 < T_) atomicMin(&way_priv[0][ji[t1]], t1);
        bool lose0 = false, lose1 = false;
        if (t0 < T_) {
            int j = ji[t0];
            if (way_priv[0][j] == t0) p[j] = t0; else lose0 = true;
        }
        if (t1 < T_) {
            int j = ji[t1];
            if (way_priv[0][j] == t1) p[j] = t1; else lose1 = true;
        }
        unsigned long long m0 = __ballot(lose0);
        unsigned long long m1 = __ballot(lose1);
        const int c0 = __popcll(m0);
        if (lose0) s_pend[__popcll(m0 & ((1ull << lane) - 1ull))] = lane;
        if (lose1) s_pend[c0 + __popcll(m1 & ((1ull << lane) - 1ull))] = lane + 64;
        if (lane == 0) s_qn = c0 + __popcll(m1);
    }

    // ---- super-iterations: up to NW speculative trees, disjoint-commit ----
    for (;;) {
        __syncthreads();                    // commits + queue visible
        const int qn = s_qn;
        if (qn <= 0) break;
        const int nact   = (qn < NW) ? qn : NW;
        const bool active = (wave < nact);
        const int  isrc   = active ? s_pend[wave] : -1;

        // committed snapshots (stable this super-iteration)
        const float u_lo = u[lane];
        const float u_hi = u[64 + lane];
        float vreg[KSLOT];
        #pragma unroll
        for (int k = 0; k < KSLOT; ++k) {
            int j = k * 64 + lane;
            vreg[k] = (j < Q_) ? v[j] : 0.0f;
        }

        unsigned int used = 0;
        float vadd[KSLOT], minv[KSLOT];
        float uisrc_acc = 0.0f;
        int jfin = Q_;

        if (active) {
            int* __restrict__ wayw = way_priv[wave];
            #pragma unroll
            for (int k = 0; k < KSLOT; ++k) { minv[k] = INF_; vadd[k] = 0.0f; }
            int j0 = Q_;
            uisrc_acc = u[isrc];
            float uicur = uisrc_acc;

            float pre[KSLOT];
            {
                const float* __restrict__ row = cb + (size_t)isrc * Q_;
                #pragma unroll
                for (int k = 0; k < KSLOT; ++k) {
                    int j = k * 64 + lane;
                    pre[k] = (j < Q_) ? row[j] : INF_;
                }
            }

            while (true) {
                float best = INF_; int bj = Q_;
                #pragma unroll
                for (int k = 0; k < KSLOT; ++k) {
                    int j = k * 64 + lane;
                    if (j < Q_ && !((used >> k) & 1u)) {
                        float cur = pre[k] - uicur - vreg[k];
                        if (cur < minv[k]) { minv[k] = cur; wayw[j] = j0; }
                        float mm = minv[k];
                        if (mm < best) { best = mm; bj = j; }
                    }
                }
                const float delta = wave_min_bcast_f(best);
                const int   j1    = wave_min_bcast_i((best == delta) ? bj : 0x7FFFFFFF);
                const int   inext = p[j1];          // committed (stable)

                // speculative prefetch of next row
                {
                    int ipre = (inext < 0) ? 0 : inext;
                    const float* __restrict__ row = cb + (size_t)ipre * Q_;
                    #pragma unroll
                    for (int k = 0; k < KSLOT; ++k) {
                        int j = k * 64 + lane;
                        pre[k] = (j < Q_) ? row[j] : INF_;
                    }
                }

                // dual updates (j1 counted FREE here, as reference/r6)
                uisrc_acc += delta;
                #pragma unroll
                for (int k = 0; k < KSLOT; ++k) {
                    int j = k * 64 + lane;
                    if (j < Q_) {
                        if ((used >> k) & 1u) vadd[k] += delta;
                        else                  minv[k] -= delta;
                    }
                }

                if (inext < 0) { jfin = j1; break; }

                if (lane == (j1 & 63)) used |= 1u << (j1 >> 6);
                {
                    const int si = __builtin_amdgcn_readfirstlane(inext);
                    const float tsel = (si < 64) ? u_lo : u_hi;
                    uicur = __int_as_float(
                        __builtin_amdgcn_readlane(__float_as_int(tsel), si & 63));
                }
                j0 = j1;
            }
        }

        // publish tree column mask (used cols + final col)
        {
            int msk = active ? (int)used : 0;
            if (active && lane == (jfin & 63)) msk |= 1 << (jfin >> 6);
            s_mask[wave][lane] = msk;
        }
        __syncthreads();

        // acceptance: greedy prefix in pend order, pairwise disjoint (wave 0)
        if (wave == 0) {
            int acc = 1;
            for (int bb = 1; bb < nact; ++bb) {
                int mb = s_mask[bb][lane];
                bool ok = true;
                for (int aa = 0; aa < bb; ++aa) {
                    if ((acc >> aa) & 1) {
                        bool hit = (s_mask[aa][lane] & mb) != 0;
                        if (__ballot(hit) != 0ull) ok = false;
                    }
                }
                if (ok) acc |= 1 << bb;
            }
            if (lane == 0) s_acc = acc;
        }
        __syncthreads();

        // commit accepted trees (disjoint => parallel-safe)
        if (active && ((s_acc >> wave) & 1)) {
            #pragma unroll
            for (int k = 0; k < KSLOT; ++k) {
                int j = k * 64 + lane;
                if (j < Q_ && ((used >> k) & 1u)) {
                    int r = p[j];                  // row matched to j (pre-augment)
                    u[r] = u[r] + vadd[k];
                    v[j] = v[j] - vadd[k];
                }
            }
            if (lane == 0) {
                u[isrc] = uisrc_acc;
                int jj = jfin;
                int* __restrict__ wayw = way_priv[wave];
                while (true) {
                    int jp = wayw[jj];
                    if (jp == Q_) { p[jj] = isrc; break; }
                    p[jj] = p[jp];
                    jj = jp;
                }
            }
        }
        __syncthreads();

        // rebuild queue (rejected keep order, go to front)
        if (tid == 0) {
            int acc = s_acc;
            int tmp[NW]; int nrej = 0;
            for (int w = 0; w < nact; ++w)
                if (!((acc >> w) & 1)) tmp[nrej++] = s_pend[w];
            for (int i = 0; i < nrej; ++i) s_pend[i] = tmp[i];
            for (int i = nact; i < qn; ++i) s_pend[nrej + i - nact] = s_pend[i];
            s_qn = qn - nact + nrej;
        }
    }

    // ---- outputs: col[t] = assigned query; rank-sort ascending by query ----
    for (int j = tid; j < Q_; j += 256) {
        int r = p[j];
        if (r >= 0) col[r] = j;
    }
    __syncthreads();
    if (tid < T_) {
        int cj = col[tid];
        int rank = 0;
        for (int t2 = 0; t2 < T_; ++t2) rank += (col[t2] < cj) ? 1 : 0;
        out_pred[b * T_ + rank] = (float)cj;
        out_tgt [b * T_ + rank] = (float)tid;
    }
}

extern "C" void kernel_launch(void* const* d_in, const int* in_sizes, int n_in,
                              void* d_out, int out_size, void* d_ws, size_t ws_size,
                              hipStream_t stream) {
    const float* logits  = (const float*)d_in[0];   // [B,Q,C]
    const float* pboxes  = (const float*)d_in[1];   // [B,Q,4]
    const int*   tlabels = (const int*)d_in[2];     // [B,T]
    const float* tboxes  = (const float*)d_in[3];   // [B,T,4]

    float* out      = (float*)d_out;
    float* cost     = out;                                   // [B,Q,T]
    float* out_pred = out + (size_t)B_ * Q_ * T_;            // [B,T]
    float* out_tgt  = out_pred + (size_t)B_ * T_;            // [B,T]

    float* costT = (float*)d_ws;  // [B,T,Q]; ws >= 23 MB proven

    dim3 gridc(NQB, B_);
    cost_kernel<<<gridc, 256, 0, stream>>>(logits, pboxes, tlabels, tboxes, cost, costT);
    hung_kernel<<<B_, 256, 0, stream>>>(costT, out_pred, out_tgt);
}

// Round 6
// 149.752 us; speedup vs baseline: 1.2824x; 1.0811x over previous
//
#include <hip/hip_runtime.h>
#include <stdint.h>

#define B_ 64
#define Q_ 900
#define T_ 100
#define C_ 256
#define INF_ 1e9f
#define QT 32       // queries per cost-kernel block
#define NQB 29      // ceil(Q_/QT)
#define NG 8        // target groups per block (tid>>5)
#define TPG 13      // targets per group (last group has 9)
#define SC 101      // s_c stride: bank=(5*qr+t)%32, 5 coprime 32 -> conflict-free
#define KSLOT 15    // ceil(Q_/64) column slots per lane (hungarian)
#define RG 4        // rows per warm-start group
#define NW 8        // waves per hung block (parallel trees) -- r6: 4 -> 8
#define HB 512      // hung block size (8 waves)

// ---------------------------------------------------------------------------
// Wave64 min-reductions via DPP (verified on HW in round 6).
// ---------------------------------------------------------------------------
#define DPP_STEP_F(x, ctrl, rmask)                                             \
    x = fminf(x, __int_as_float(__builtin_amdgcn_update_dpp(                   \
            0x7F800000 /*+inf*/, __float_as_int(x), ctrl, rmask, 0xF, false)))
#define DPP_STEP_I(x, ctrl, rmask)                                             \
    x = min(x, __builtin_amdgcn_update_dpp(                                    \
            0x7FFFFFFF, x, ctrl, rmask, 0xF, false))

__device__ __forceinline__ float wave_min_bcast_f(float x) {
    DPP_STEP_F(x, 0x111, 0xF);   // row_shr:1
    DPP_STEP_F(x, 0x112, 0xF);   // row_shr:2
    DPP_STEP_F(x, 0x114, 0xF);   // row_shr:4
    DPP_STEP_F(x, 0x118, 0xF);   // row_shr:8
    DPP_STEP_F(x, 0x142, 0xA);   // row_bcast:15 -> rows 1,3
    DPP_STEP_F(x, 0x143, 0xC);   // row_bcast:31 -> rows 2,3
    return __int_as_float(__builtin_amdgcn_readlane(__float_as_int(x), 63));
}
__device__ __forceinline__ int wave_min_bcast_i(int x) {
    DPP_STEP_I(x, 0x111, 0xF);
    DPP_STEP_I(x, 0x112, 0xF);
    DPP_STEP_I(x, 0x114, 0xF);
    DPP_STEP_I(x, 0x118, 0xF);
    DPP_STEP_I(x, 0x142, 0xA);
    DPP_STEP_I(x, 0x143, 0xC);
    return __builtin_amdgcn_readlane(x, 63);
}

// ---------------------------------------------------------------------------
// Kernel 1: cost matrix (unchanged from round 5 -- verified, off the top-5).
// ---------------------------------------------------------------------------
__global__ __launch_bounds__(256) void cost_kernel(
    const float* __restrict__ logits,   // [B,Q,C]
    const float* __restrict__ pboxes,   // [B,Q,4] cxcywh
    const int*   __restrict__ tlabels,  // [B,T]
    const float* __restrict__ tboxes,   // [B,T,4] cxcywh
    float* __restrict__ cost_out,       // [B,Q,T]
    float* __restrict__ costT_out)      // [B,T,Q]
{
    const int b   = blockIdx.y;
    const int q0  = blockIdx.x * QT;
    const int tid = threadIdx.x;

    __shared__ float  s_log[QT][C_ + 1]; // 32 x 257 floats = 32.9KB
    __shared__ float  s_c[QT][SC];       // transpose buffer, 12.9KB
    __shared__ float4 s_tb4[T_];         // target cxcywh (16B aligned by type)
    __shared__ int    s_lab[T_];

    // ---- stage all 100 targets once ----
    if (tid < T_) {
        s_tb4[tid] = *reinterpret_cast<const float4*>(tboxes + ((size_t)b * T_ + tid) * 4);
        s_lab[tid] = tlabels[b * T_ + tid];
    }

    // ---- stage 32x256 logits tile, coalesced, once from HBM ----
    const float* __restrict__ lgb = logits + (size_t)b * Q_ * C_;
    #pragma unroll
    for (int it = 0; it < 8; ++it) {
        const int idx = it * 256 + tid;                  // 0..2047 float4 slots
        const int row = (idx >> 4) & 31;                 // idx[8:4]
        const int c4  = (idx & 15) | ((idx >> 9) << 4);  // idx[3:0] | idx[10:9]<<4
        const int q   = q0 + row;
        float4 vv = make_float4(0.f, 0.f, 0.f, 0.f);
        if (q < Q_)
            vv = *reinterpret_cast<const float4*>(lgb + (size_t)q * C_ + (c4 << 2));
        float* d = &s_log[row][c4 << 2];
        d[0] = vv.x; d[1] = vv.y; d[2] = vv.z; d[3] = vv.w;
    }
    __syncthreads();

    const int qr  = tid & 31;
    const int q   = q0 + qr;
    const bool qok = (q < Q_);
    const int qc  = qok ? q : (Q_ - 1);    // clamped for safe (discarded) loads
    const int g   = tid >> 5;              // target group 0..7

    const float4 pb = *reinterpret_cast<const float4*>(pboxes + ((size_t)b * Q_ + qc) * 4);
    const float pcx = pb.x, pcy = pb.y, pw = pb.z, ph = pb.w;
    const float ax0 = pcx - 0.5f * pw, ay0 = pcy - 0.5f * ph;
    const float ax1 = pcx + 0.5f * pw, ay1 = pcy + 0.5f * ph;
    const float area_a = (ax1 - ax0) * (ay1 - ay0);   // keep reference arithmetic

    const float* __restrict__ srow = s_log[qr];
    const int tbase = g * TPG;                 // 0,13,...,91
    const int tcnt  = (T_ - tbase < TPG) ? (T_ - tbase) : TPG;   // 13 or 9

    float c[TPG];
    #pragma unroll
    for (int k = 0; k < TPG; ++k) {
        const int t = tbase + ((k < tcnt) ? k : 0);               // clamp (dup work, no OOB)
        const float4 tb = s_tb4[t];                               // broadcast b128
        const float cls = -srow[s_lab[t]];                        // conflict-free gather
        const float l1 = fabsf(pcx - tb.x) + fabsf(pcy - tb.y)
                       + fabsf(pw  - tb.z) + fabsf(ph  - tb.w);
        const float bx0 = tb.x - 0.5f * tb.z, by0 = tb.y - 0.5f * tb.w;
        const float bx1 = tb.x + 0.5f * tb.z, by1 = tb.y + 0.5f * tb.w;
        const float area_b = (bx1 - bx0) * (by1 - by0);
        const float ltx = fmaxf(ax0, bx0), lty = fmaxf(ay0, by0);
        const float rbx = fminf(ax1, bx1), rby = fminf(ay1, by1);
        const float wx = fmaxf(rbx - ltx, 0.0f), wy = fmaxf(rby - lty, 0.0f);
        const float inter = wx * wy;
        const float uni = area_a + area_b - inter;
        const float iou = inter / uni;
        const float ex0 = fminf(ax0, bx0), ey0 = fminf(ay0, by0);
        const float ex1 = fmaxf(ax1, bx1), ey1 = fmaxf(ay1, by1);
        const float ew = fmaxf(ex1 - ex0, 0.0f), eh = fmaxf(ey1 - ey0, 0.0f);
        const float enc = ew * eh;
        const float giou = iou - (enc - uni) / enc;
        c[k] = cls + l1 - giou;
    }

    // costT [B,T,Q]: fixed t per store, q contiguous across half-wave -> coalesced
    if (qok) {
        float* __restrict__ ct = costT_out + (size_t)b * T_ * Q_ + (size_t)tbase * Q_ + q;
        #pragma unroll
        for (int k = 0; k < TPG; ++k)
            if (k < tcnt) ct[(size_t)k * Q_] = c[k];

        // transpose into LDS: bank=(5*qr+t)%32, bijective per half-wave -> free
        #pragma unroll
        for (int k = 0; k < TPG; ++k)
            if (k < tcnt) s_c[qr][tbase + k] = c[k];
    }
    __syncthreads();

    // cost [B,Q,T]: the block's 32x100 tile is CONTIGUOUS (row stride = T_).
    const int nrows = (Q_ - q0 < QT) ? (Q_ - q0) : QT;
    const int ntot  = nrows * T_;
    float* __restrict__ tile = cost_out + ((size_t)b * Q_ + q0) * T_;
    for (int idx = tid; idx < ntot; idx += 256) {
        const int r = idx / T_;
        const int t = idx - r * T_;
        tile[idx] = s_c[r][t];
    }
}

// ---------------------------------------------------------------------------
// Kernel 2: exact Hungarian. r6: NW=4 -> 8 trees on 512 threads.
// r5 profile: 64 blocks x 4 waves = 1 wave/SIMD, zero latency hiding;
// ~400-500cy exposed per SAP iteration (L2 row load + LDS + DPP chains).
// 8 waves/block = 2 waves/SIMD (TLP hides row-load latency) + up to 8
// speculative trees per super-iteration (fewer super-iterations).
// ---------------------------------------------------------------------------
__global__ __launch_bounds__(HB) void hung_kernel(
    const float* __restrict__ costT,   // [B,T,Q]
    float* __restrict__ out_pred,      // [B,T] as float
    float* __restrict__ out_tgt)       // [B,T] as float
{
    const int b    = blockIdx.x;
    const int tid  = threadIdx.x;
    const int lane = tid & 63;
    const int wave = tid >> 6;
    const float* __restrict__ cb = costT + (size_t)b * T_ * Q_;

    __shared__ float u[128];             // [100] + pad for snapshot reads
    __shared__ float v[Q_];              // committed column duals
    __shared__ int   p[Q_];              // committed matching (col -> row)
    __shared__ int   way_priv[NW][Q_];   // per-wave predecessor arrays
    __shared__ int   ji[T_];
    __shared__ int   s_pend[T_];
    __shared__ int   col[T_];
    __shared__ int   s_mask[NW][64];     // per-wave tree column masks
    __shared__ int   s_qn, s_acc;

    // ---- init committed state ----
    for (int j = tid; j < Q_; j += HB) {
        p[j] = -1; v[j] = 0.0f; way_priv[0][j] = 0x7FFFFFFF;  // [0] = greedy scratch
    }
    if (tid >= 100 && tid < 128) u[tid] = INF_;

    // ---- warm start: u[i] = row min, ji[i] = first argmin (8 waves) ----
    for (int g = wave * RG; g < T_; g += NW * RG) {
        float rv[RG][KSLOT];
        #pragma unroll
        for (int r = 0; r < RG; ++r) {
            const float* __restrict__ row = cb + (size_t)(g + r) * Q_;
            #pragma unroll
            for (int k = 0; k < KSLOT; ++k) {
                int j = k * 64 + lane;
                rv[r][k] = (j < Q_) ? row[j] : INF_;
            }
        }
        #pragma unroll
        for (int r = 0; r < RG; ++r) {
            float m = INF_; int mj = Q_;
            #pragma unroll
            for (int k = 0; k < KSLOT; ++k) {
                int j = k * 64 + lane;
                if (rv[r][k] < m) { m = rv[r][k]; mj = j; }   // strict <: first index
            }
            const float mm = wave_min_bcast_f(m);
            const int   gj = wave_min_bcast_i((m == mm) ? mj : 0x7FFFFFFF);
            if (lane == 0) { u[g + r] = mm; ji[g + r] = gj; }
        }
    }
    __syncthreads();

    // ---- parallel greedy (wave 0): column winner = smallest suitor row ----
    if (wave == 0) {
        int t0 = lane, t1 = lane + 64;
        if (t0 < T_) atomicMin(&way_priv[0][ji[t0]], t0);
        if (t1 < T_) atomicMin(&way_priv[0][ji[t1]], t1);
        bool lose0 = false, lose1 = false;
        if (t0 < T_) {
            int j = ji[t0];
            if (way_priv[0][j] == t0) p[j] = t0; else lose0 = true;
        }
        if (t1 < T_) {
            int j = ji[t1];
            if (way_priv[0][j] == t1) p[j] = t1; else lose1 = true;
        }
        unsigned long long m0 = __ballot(lose0);
        unsigned long long m1 = __ballot(lose1);
        const int c0 = __popcll(m0);
        if (lose0) s_pend[__popcll(m0 & ((1ull << lane) - 1ull))] = lane;
        if (lose1) s_pend[c0 + __popcll(m1 & ((1ull << lane) - 1ull))] = lane + 64;
        if (lane == 0) s_qn = c0 + __popcll(m1);
    }

    // ---- super-iterations: up to NW speculative trees, disjoint-commit ----
    for (;;) {
        __syncthreads();                    // commits + queue visible
        const int qn = s_qn;
        if (qn <= 0) break;
        const int nact   = (qn < NW) ? qn : NW;
        const bool active = (wave < nact);
        const int  isrc   = active ? s_pend[wave] : -1;

        // committed snapshots (stable this super-iteration)
        const float u_lo = u[lane];
        const float u_hi = u[64 + lane];
        float vreg[KSLOT];
        #pragma unroll
        for (int k = 0; k < KSLOT; ++k) {
            int j = k * 64 + lane;
            vreg[k] = (j < Q_) ? v[j] : 0.0f;
        }

        unsigned int used = 0;
        float vadd[KSLOT], minv[KSLOT];
        float uisrc_acc = 0.0f;
        int jfin = Q_;

        if (active) {
            int* __restrict__ wayw = way_priv[wave];
            #pragma unroll
            for (int k = 0; k < KSLOT; ++k) { minv[k] = INF_; vadd[k] = 0.0f; }
            int j0 = Q_;
            uisrc_acc = u[isrc];
            float uicur = uisrc_acc;

            float pre[KSLOT];
            {
                const float* __restrict__ row = cb + (size_t)isrc * Q_;
                #pragma unroll
                for (int k = 0; k < KSLOT; ++k) {
                    int j = k * 64 + lane;
                    pre[k] = (j < Q_) ? row[j] : INF_;
                }
            }

            while (true) {
                float best = INF_; int bj = Q_;
                #pragma unroll
                for (int k = 0; k < KSLOT; ++k) {
                    int j = k * 64 + lane;
                    if (j < Q_ && !((used >> k) & 1u)) {
                        float cur = pre[k] - uicur - vreg[k];
                        if (cur < minv[k]) { minv[k] = cur; wayw[j] = j0; }
                        float mm = minv[k];
                        if (mm < best) { best = mm; bj = j; }
                    }
                }
                const float delta = wave_min_bcast_f(best);
                const int   j1    = wave_min_bcast_i((best == delta) ? bj : 0x7FFFFFFF);
                const int   inext = p[j1];          // committed (stable)

                // speculative prefetch of next row
                {
                    int ipre = (inext < 0) ? 0 : inext;
                    const float* __restrict__ row = cb + (size_t)ipre * Q_;
                    #pragma unroll
                    for (int k = 0; k < KSLOT; ++k) {
                        int j = k * 64 + lane;
                        pre[k] = (j < Q_) ? row[j] : INF_;
                    }
                }

                // dual updates (j1 counted FREE here, as reference/r6)
                uisrc_acc += delta;
                #pragma unroll
                for (int k = 0; k < KSLOT; ++k) {
                    int j = k * 64 + lane;
                    if (j < Q_) {
                        if ((used >> k) & 1u) vadd[k] += delta;
                        else                  minv[k] -= delta;
                    }
                }

                if (inext < 0) { jfin = j1; break; }

                if (lane == (j1 & 63)) used |= 1u << (j1 >> 6);
                {
                    const int si = __builtin_amdgcn_readfirstlane(inext);
                    const float tsel = (si < 64) ? u_lo : u_hi;
                    uicur = __int_as_float(
                        __builtin_amdgcn_readlane(__float_as_int(tsel), si & 63));
                }
                j0 = j1;
            }
        }

        // publish tree column mask (used cols + final col)
        {
            int msk = active ? (int)used : 0;
            if (active && lane == (jfin & 63)) msk |= 1 << (jfin >> 6);
            s_mask[wave][lane] = msk;
        }
        __syncthreads();

        // acceptance: greedy prefix in pend order, pairwise disjoint (wave 0)
        if (wave == 0) {
            int acc = 1;
            for (int bb = 1; bb < nact; ++bb) {
                int mb = s_mask[bb][lane];
                bool ok = true;
                for (int aa = 0; aa < bb; ++aa) {
                    if ((acc >> aa) & 1) {
                        bool hit = (s_mask[aa][lane] & mb) != 0;
                        if (__ballot(hit) != 0ull) ok = false;
                    }
                }
                if (ok) acc |= 1 << bb;
            }
            if (lane == 0) s_acc = acc;
        }
        __syncthreads();

        // commit accepted trees (disjoint => parallel-safe)
        if (active && ((s_acc >> wave) & 1)) {
            #pragma unroll
            for (int k = 0; k < KSLOT; ++k) {
                int j = k * 64 + lane;
                if (j < Q_ && ((used >> k) & 1u)) {
                    int r = p[j];                  // row matched to j (pre-augment)
                    u[r] = u[r] + vadd[k];
                    v[j] = v[j] - vadd[k];
                }
            }
            if (lane == 0) {
                u[isrc] = uisrc_acc;
                int jj = jfin;
                int* __restrict__ wayw = way_priv[wave];
                while (true) {
                    int jp = wayw[jj];
                    if (jp == Q_) { p[jj] = isrc; break; }
                    p[jj] = p[jp];
                    jj = jp;
                }
            }
        }
        __syncthreads();

        // rebuild queue (rejected keep order, go to front)
        if (tid == 0) {
            int acc = s_acc;
            int tmp[NW]; int nrej = 0;
            for (int w = 0; w < nact; ++w)
                if (!((acc >> w) & 1)) tmp[nrej++] = s_pend[w];
            for (int i = 0; i < nrej; ++i) s_pend[i] = tmp[i];
            for (int i = nact; i < qn; ++i) s_pend[nrej + i - nact] = s_pend[i];
            s_qn = qn - nact + nrej;
        }
    }

    // ---- outputs: col[t] = assigned query; rank-sort ascending by query ----
    for (int j = tid; j < Q_; j += HB) {
        int r = p[j];
        if (r >= 0) col[r] = j;
    }
    __syncthreads();
    if (tid < T_) {
        int cj = col[tid];
        int rank = 0;
        for (int t2 = 0; t2 < T_; ++t2) rank += (col[t2] < cj) ? 1 : 0;
        out_pred[b * T_ + rank] = (float)cj;
        out_tgt [b * T_ + rank] = (float)tid;
    }
}

extern "C" void kernel_launch(void* const* d_in, const int* in_sizes, int n_in,
                              void* d_out, int out_size, void* d_ws, size_t ws_size,
                              hipStream_t stream) {
    const float* logits  = (const float*)d_in[0];   // [B,Q,C]
    const float* pboxes  = (const float*)d_in[1];   // [B,Q,4]
    const int*   tlabels = (const int*)d_in[2];     // [B,T]
    const float* tboxes  = (const float*)d_in[3];   // [B,T,4]

    float* out      = (float*)d_out;
    float* cost     = out;                                   // [B,Q,T]
    float* out_pred = out + (size_t)B_ * Q_ * T_;            // [B,T]
    float* out_tgt  = out_pred + (size_t)B_ * T_;            // [B,T]

    float* costT = (float*)d_ws;  // [B,T,Q]; ws >= 23 MB proven

    dim3 gridc(NQB, B_);
    cost_kernel<<<gridc, 256, 0, stream>>>(logits, pboxes, tlabels, tboxes, cost, costT);
    hung_kernel<<<B_, HB, 0, stream>>>(costT, out_pred, out_tgt);
}

// Round 7
// 141.319 us; speedup vs baseline: 1.3589x; 1.0597x over previous
//
#include <hip/hip_runtime.h>
#include <stdint.h>

#define B_ 64
#define Q_ 900
#define T_ 100
#define C_ 256
#define INF_ 1e9f
#define QT 32       // queries per tile
#define TBLK 12     // cost blocks per batch; tiles bx, bx+12, bx+24
#define NG 8        // target groups per block (tid>>5)
#define TPG 13      // targets per group (last group has 9)
#define SC 101      // s_c stride: bank=(5*qr+t)%32 -> conflict-free transpose
#define KSLOT 15    // ceil(Q_/64) column slots per lane (hungarian)
#define RG 4        // rows per warm-start group
#define NW 8        // waves per hung block (parallel trees)
#define HB 512      // hung block size (8 waves)

// ---------------------------------------------------------------------------
// Wave64 min-reductions via DPP (verified on HW).
// ---------------------------------------------------------------------------
#define DPP_STEP_F(x, ctrl, rmask)                                             \
    x = fminf(x, __int_as_float(__builtin_amdgcn_update_dpp(                   \
            0x7F800000 /*+inf*/, __float_as_int(x), ctrl, rmask, 0xF, false)))
#define DPP_STEP_I(x, ctrl, rmask)                                             \
    x = min(x, __builtin_amdgcn_update_dpp(                                    \
            0x7FFFFFFF, x, ctrl, rmask, 0xF, false))

__device__ __forceinline__ float wave_min_bcast_f(float x) {
    DPP_STEP_F(x, 0x111, 0xF);   // row_shr:1
    DPP_STEP_F(x, 0x112, 0xF);   // row_shr:2
    DPP_STEP_F(x, 0x114, 0xF);   // row_shr:4
    DPP_STEP_F(x, 0x118, 0xF);   // row_shr:8
    DPP_STEP_F(x, 0x142, 0xA);   // row_bcast:15 -> rows 1,3
    DPP_STEP_F(x, 0x143, 0xC);   // row_bcast:31 -> rows 2,3
    return __int_as_float(__builtin_amdgcn_readlane(__float_as_int(x), 63));
}
__device__ __forceinline__ int wave_min_bcast_i(int x) {
    DPP_STEP_I(x, 0x111, 0xF);
    DPP_STEP_I(x, 0x112, 0xF);
    DPP_STEP_I(x, 0x114, 0xF);
    DPP_STEP_I(x, 0x118, 0xF);
    DPP_STEP_I(x, 0x142, 0xA);
    DPP_STEP_I(x, 0x143, 0xC);
    return __builtin_amdgcn_readlane(x, 63);
}

// ---------------------------------------------------------------------------
// Kernel 1: cost matrix, SOFTWARE-PIPELINED (r7).
// r6 diagnosis: bulk-synchronous {stage|barrier|compute|barrier|store} left
// HBM at 24% and VALU at 27% -- the pipes alternate instead of overlapping
// (r4's occupancy null: doubling blocks/CU halved per-block work, so
// concurrent HBM demand was unchanged). Fix (T14 async-stage): 768 blocks
// (3/CU, all resident), each owns 2-3 q-tiles; next tile's global loads are
// issued into REGISTERS before compute, ds_written to LDS after the
// post-compute barrier -- HBM latency hides under the compute phase.
// ---------------------------------------------------------------------------
__global__ __launch_bounds__(256) void cost_kernel(
    const float* __restrict__ logits,   // [B,Q,C]
    const float* __restrict__ pboxes,   // [B,Q,4] cxcywh
    const int*   __restrict__ tlabels,  // [B,T]
    const float* __restrict__ tboxes,   // [B,T,4] cxcywh
    float* __restrict__ cost_out,       // [B,Q,T]
    float* __restrict__ costT_out)      // [B,T,Q]
{
    const int b   = blockIdx.y;
    const int bx  = blockIdx.x;          // 0..11
    const int tid = threadIdx.x;

    __shared__ float  s_log[QT][C_ + 1]; // 32 x 257 floats = 32.9KB
    __shared__ float  s_c[QT][SC];       // transpose buffer, 12.9KB
    __shared__ float4 s_tb4[T_];
    __shared__ int    s_lab[T_];

    // ---- stage all 100 targets once ----
    if (tid < T_) {
        s_tb4[tid] = *reinterpret_cast<const float4*>(tboxes + ((size_t)b * T_ + tid) * 4);
        s_lab[tid] = tlabels[b * T_ + tid];
    }

    const float* __restrict__ lgb = logits + (size_t)b * Q_ * C_;
    const int nt = (bx < 5) ? 3 : 2;     // tiles bx, bx+12, (bx+24 if bx<5)
    const int qr = tid & 31;
    const int g  = tid >> 5;
    const int tbase = g * TPG;
    const int tcnt  = (T_ - tbase < TPG) ? (T_ - tbase) : TPG;

    // staging lane map: row=idx[8:4], c4=idx[3:0]|idx[10:9]<<4
    //  -> global 4x256B segments/wave; ds_write banks 2-way (free)
    int srow_[8], sc4_[8];
    #pragma unroll
    for (int it = 0; it < 8; ++it) {
        const int idx = it * 256 + tid;
        srow_[it] = (idx >> 4) & 31;
        sc4_[it]  = (idx & 15) | ((idx >> 9) << 4);
    }

    float4 rr[8];
    float4 pbc, pbn;

    // ---- prologue: load tile 0 (regs), write LDS, load pboxes row ----
    {
        const int q0 = bx * QT;
        #pragma unroll
        for (int it = 0; it < 8; ++it) {
            const int q = q0 + srow_[it];
            rr[it] = (q < Q_)
                ? *reinterpret_cast<const float4*>(lgb + (size_t)q * C_ + (sc4_[it] << 2))
                : make_float4(0.f, 0.f, 0.f, 0.f);
        }
        const int q  = q0 + qr;
        const int qc = (q < Q_) ? q : (Q_ - 1);
        pbc = *reinterpret_cast<const float4*>(pboxes + ((size_t)b * Q_ + qc) * 4);
        #pragma unroll
        for (int it = 0; it < 8; ++it) {
            float* d = &s_log[srow_[it]][sc4_[it] << 2];
            d[0] = rr[it].x; d[1] = rr[it].y; d[2] = rr[it].z; d[3] = rr[it].w;
        }
    }
    __syncthreads();

    for (int i = 0; i < nt; ++i) {
        const int q0  = (bx + TBLK * i) * QT;
        const int q   = q0 + qr;
        const bool qok = (q < Q_);
        const bool more = (i + 1 < nt);

        // ---- 1. issue next tile's loads into registers (latency hidden by 2.) ----
        if (more) {
            const int q0n = (bx + TBLK * (i + 1)) * QT;
            #pragma unroll
            for (int it = 0; it < 8; ++it) {
                const int qn = q0n + srow_[it];
                rr[it] = (qn < Q_)
                    ? *reinterpret_cast<const float4*>(lgb + (size_t)qn * C_ + (sc4_[it] << 2))
                    : make_float4(0.f, 0.f, 0.f, 0.f);
            }
            const int qn  = q0n + qr;
            const int qcn = (qn < Q_) ? qn : (Q_ - 1);
            pbn = *reinterpret_cast<const float4*>(pboxes + ((size_t)b * Q_ + qcn) * 4);
        }

        // ---- 2. compute tile i from LDS ----
        const float pcx = pbc.x, pcy = pbc.y, pw = pbc.z, ph = pbc.w;
        const float ax0 = pcx - 0.5f * pw, ay0 = pcy - 0.5f * ph;
        const float ax1 = pcx + 0.5f * pw, ay1 = pcy + 0.5f * ph;
        const float area_a = (ax1 - ax0) * (ay1 - ay0);
        const float* __restrict__ srow = s_log[qr];

        float c[TPG];
        #pragma unroll
        for (int k = 0; k < TPG; ++k) {
            const int t = tbase + ((k < tcnt) ? k : 0);
            const float4 tb = s_tb4[t];
            const float cls = -srow[s_lab[t]];
            const float l1 = fabsf(pcx - tb.x) + fabsf(pcy - tb.y)
                           + fabsf(pw  - tb.z) + fabsf(ph  - tb.w);
            const float bx0 = tb.x - 0.5f * tb.z, by0 = tb.y - 0.5f * tb.w;
            const float bx1 = tb.x + 0.5f * tb.z, by1 = tb.y + 0.5f * tb.w;
            const float area_b = (bx1 - bx0) * (by1 - by0);
            const float ltx = fmaxf(ax0, bx0), lty = fmaxf(ay0, by0);
            const float rbx = fminf(ax1, bx1), rby = fminf(ay1, by1);
            const float wx = fmaxf(rbx - ltx, 0.0f), wy = fmaxf(rby - lty, 0.0f);
            const float inter = wx * wy;
            const float uni = area_a + area_b - inter;
            const float iou = inter / uni;
            const float ex0 = fminf(ax0, bx0), ey0 = fminf(ay0, by0);
            const float ex1 = fmaxf(ax1, bx1), ey1 = fmaxf(ay1, by1);
            const float ew = fmaxf(ex1 - ex0, 0.0f), eh = fmaxf(ey1 - ey0, 0.0f);
            const float enc = ew * eh;
            const float giou = iou - (enc - uni) / enc;
            c[k] = cls + l1 - giou;
        }

        // ---- 3. costT [B,T,Q] stores (q contiguous per half-wave) ----
        if (qok) {
            float* __restrict__ ct = costT_out + (size_t)b * T_ * Q_ + (size_t)tbase * Q_ + q;
            #pragma unroll
            for (int k = 0; k < TPG; ++k)
                if (k < tcnt) ct[(size_t)k * Q_] = c[k];
        }

        // ---- 4. barrier: all waves done reading s_log / s_c free ----
        __syncthreads();

        // ---- 5. transpose into s_c; ds_write prefetched tile into s_log ----
        if (qok) {
            #pragma unroll
            for (int k = 0; k < TPG; ++k)
                if (k < tcnt) s_c[qr][tbase + k] = c[k];
        }
        if (more) {
            #pragma unroll
            for (int it = 0; it < 8; ++it) {
                float* d = &s_log[srow_[it]][sc4_[it] << 2];
                d[0] = rr[it].x; d[1] = rr[it].y; d[2] = rr[it].z; d[3] = rr[it].w;
            }
        }

        // ---- 6. barrier: s_c and next s_log ready ----
        __syncthreads();

        // ---- 7. cost [B,Q,T]: contiguous 32x100 tile writeout ----
        const int nrows = (Q_ - q0 < QT) ? (Q_ - q0) : QT;
        const int ntot  = nrows * T_;
        float* __restrict__ tile = cost_out + ((size_t)b * Q_ + q0) * T_;
        for (int idx = tid; idx < ntot; idx += 256) {
            const int r = idx / T_;
            const int t = idx - r * T_;
            tile[idx] = s_c[r][t];
        }

        pbc = pbn;
    }
}

// ---------------------------------------------------------------------------
// Kernel 2: exact Hungarian, NW=8 speculatively-parallel SAP trees per batch.
// (unchanged from the verified round-6 version)
// ---------------------------------------------------------------------------
__global__ __launch_bounds__(HB) void hung_kernel(
    const float* __restrict__ costT,   // [B,T,Q]
    float* __restrict__ out_pred,      // [B,T] as float
    float* __restrict__ out_tgt)       // [B,T] as float
{
    const int b    = blockIdx.x;
    const int tid  = threadIdx.x;
    const int lane = tid & 63;
    const int wave = tid >> 6;
    const float* __restrict__ cb = costT + (size_t)b * T_ * Q_;

    __shared__ float u[128];             // [100] + pad for snapshot reads
    __shared__ float v[Q_];              // committed column duals
    __shared__ int   p[Q_];              // committed matching (col -> row)
    __shared__ int   way_priv[NW][Q_];   // per-wave predecessor arrays
    __shared__ int   ji[T_];
    __shared__ int   s_pend[T_];
    __shared__ int   col[T_];
    __shared__ int   s_mask[NW][64];     // per-wave tree column masks
    __shared__ int   s_qn, s_acc;

    // ---- init committed state ----
    for (int j = tid; j < Q_; j += HB) {
        p[j] = -1; v[j] = 0.0f; way_priv[0][j] = 0x7FFFFFFF;  // [0] = greedy scratch
    }
    if (tid >= 100 && tid < 128) u[tid] = INF_;

    // ---- warm start: u[i] = row min, ji[i] = first argmin (8 waves) ----
    for (int g = wave * RG; g < T_; g += NW * RG) {
        float rv[RG][KSLOT];
        #pragma unroll
        for (int r = 0; r < RG; ++r) {
            const float* __restrict__ row = cb + (size_t)(g + r) * Q_;
            #pragma unroll
            for (int k = 0; k < KSLOT; ++k) {
                int j = k * 64 + lane;
                rv[r][k] = (j < Q_) ? row[j] : INF_;
            }
        }
        #pragma unroll
        for (int r = 0; r < RG; ++r) {
            float m = INF_; int mj = Q_;
            #pragma unroll
            for (int k = 0; k < KSLOT; ++k) {
                int j = k * 64 + lane;
                if (rv[r][k] < m) { m = rv[r][k]; mj = j; }   // strict <: first index
            }
            const float mm = wave_min_bcast_f(m);
            const int   gj = wave_min_bcast_i((m == mm) ? mj : 0x7FFFFFFF);
            if (lane == 0) { u[g + r] = mm; ji[g + r] = gj; }
        }
    }
    __syncthreads();

    // ---- parallel greedy (wave 0): column winner = smallest suitor row ----
    if (wave == 0) {
        int t0 = lane, t1 = lane + 64;
        if (t0 < T_) atomicMin(&way_priv[0][ji[t0]], t0);
        if (t1 < T_) atomicMin(&way_priv[0][ji[t1]], t1);
        bool lose0 = false, lose1 = false;
        if (t0 < T_) {
            int j = ji[t0];
            if (way_priv[0][j] == t0) p[j] = t0; else lose0 = true;
        }
        if (t1 < T_) {
            int j = ji[t1];
            if (way_priv[0][j] == t1) p[j] = t1; else lose1 = true;
        }
        unsigned long long m0 = __ballot(lose0);
        unsigned long long m1 = __ballot(lose1);
        const int c0 = __popcll(m0);
        if (lose0) s_pend[__popcll(m0 & ((1ull << lane) - 1ull))] = lane;
        if (lose1) s_pend[c0 + __popcll(m1 & ((1ull << lane) - 1ull))] = lane + 64;
        if (lane == 0) s_qn = c0 + __popcll(m1);
    }

    // ---- super-iterations: up to NW speculative trees, disjoint-commit ----
    for (;;) {
        __syncthreads();                    // commits + queue visible
        const int qn = s_qn;
        if (qn <= 0) break;
        const int nact   = (qn < NW) ? qn : NW;
        const bool active = (wave < nact);
        const int  isrc   = active ? s_pend[wave] : -1;

        // committed snapshots (stable this super-iteration)
        const float u_lo = u[lane];
        const float u_hi = u[64 + lane];
        float vreg[KSLOT];
        #pragma unroll
        for (int k = 0; k < KSLOT; ++k) {
            int j = k * 64 + lane;
            vreg[k] = (j < Q_) ? v[j] : 0.0f;
        }

        unsigned int used = 0;
        float vadd[KSLOT], minv[KSLOT];
        float uisrc_acc = 0.0f;
        int jfin = Q_;

        if (active) {
            int* __restrict__ wayw = way_priv[wave];
            #pragma unroll
            for (int k = 0; k < KSLOT; ++k) { minv[k] = INF_; vadd[k] = 0.0f; }
            int j0 = Q_;
            uisrc_acc = u[isrc];
            float uicur = uisrc_acc;

            float pre[KSLOT];
            {
                const float* __restrict__ row = cb + (size_t)isrc * Q_;
                #pragma unroll
                for (int k = 0; k < KSLOT; ++k) {
                    int j = k * 64 + lane;
                    pre[k] = (j < Q_) ? row[j] : INF_;
                }
            }

            while (true) {
                float best = INF_; int bj = Q_;
                #pragma unroll
                for (int k = 0; k < KSLOT; ++k) {
                    int j = k * 64 + lane;
                    if (j < Q_ && !((used >> k) & 1u)) {
                        float cur = pre[k] - uicur - vreg[k];
                        if (cur < minv[k]) { minv[k] = cur; wayw[j] = j0; }
                        float mm = minv[k];
                        if (mm < best) { best = mm; bj = j; }
                    }
                }
                const float delta = wave_min_bcast_f(best);
                const int   j1    = wave_min_bcast_i((best == delta) ? bj : 0x7FFFFFFF);
                const int   inext = p[j1];          // committed (stable)

                // speculative prefetch of next row
                {
                    int ipre = (inext < 0) ? 0 : inext;
                    const float* __restrict__ row = cb + (size_t)ipre * Q_;
                    #pragma unroll
                    for (int k = 0; k < KSLOT; ++k) {
                        int j = k * 64 + lane;
                        pre[k] = (j < Q_) ? row[j] : INF_;
                    }
                }

                // dual updates (j1 counted FREE here, as reference/r6)
                uisrc_acc += delta;
                #pragma unroll
                for (int k = 0; k < KSLOT; ++k) {
                    int j = k * 64 + lane;
                    if (j < Q_) {
                        if ((used >> k) & 1u) vadd[k] += delta;
                        else                  minv[k] -= delta;
                    }
                }

                if (inext < 0) { jfin = j1; break; }

                if (lane == (j1 & 63)) used |= 1u << (j1 >> 6);
                {
                    const int si = __builtin_amdgcn_readfirstlane(inext);
                    const float tsel = (si < 64) ? u_lo : u_hi;
                    uicur = __int_as_float(
                        __builtin_amdgcn_readlane(__float_as_int(tsel), si & 63));
                }
                j0 = j1;
            }
        }

        // publish tree column mask (used cols + final col)
        {
            int msk = active ? (int)used : 0;
            if (active && lane == (jfin & 63)) msk |= 1 << (jfin >> 6);
            s_mask[wave][lane] = msk;
        }
        __syncthreads();

        // acceptance: greedy prefix in pend order, pairwise disjoint (wave 0)
        if (wave == 0) {
            int acc = 1;
            for (int bb = 1; bb < nact; ++bb) {
                int mb = s_mask[bb][lane];
                bool ok = true;
                for (int aa = 0; aa < bb; ++aa) {
                    if ((acc >> aa) & 1) {
                        bool hit = (s_mask[aa][lane] & mb) != 0;
                        if (__ballot(hit) != 0ull) ok = false;
                    }
                }
                if (ok) acc |= 1 << bb;
            }
            if (lane == 0) s_acc = acc;
        }
        __syncthreads();

        // commit accepted trees (disjoint => parallel-safe)
        if (active && ((s_acc >> wave) & 1)) {
            #pragma unroll
            for (int k = 0; k < KSLOT; ++k) {
                int j = k * 64 + lane;
                if (j < Q_ && ((used >> k) & 1u)) {
                    int r = p[j];                  // row matched to j (pre-augment)
                    u[r] = u[r] + vadd[k];
                    v[j] = v[j] - vadd[k];
                }
            }
            if (lane == 0) {
                u[isrc] = uisrc_acc;
                int jj = jfin;
                int* __restrict__ wayw = way_priv[wave];
                while (true) {
                    int jp = wayw[jj];
                    if (jp == Q_) { p[jj] = isrc; break; }
                    p[jj] = p[jp];
                    jj = jp;
                }
            }
        }
        __syncthreads();

        // rebuild queue (rejected keep order, go to front)
        if (tid == 0) {
            int acc = s_acc;
            int tmp[NW]; int nrej = 0;
            for (int w = 0; w < nact; ++w)
                if (!((acc >> w) & 1)) tmp[nrej++] = s_pend[w];
            for (int i = 0; i < nrej; ++i) s_pend[i] = tmp[i];
            for (int i = nact; i < qn; ++i) s_pend[nrej + i - nact] = s_pend[i];
            s_qn = qn - nact + nrej;
        }
    }

    // ---- outputs: col[t] = assigned query; rank-sort ascending by query ----
    for (int j = tid; j < Q_; j += HB) {
        int r = p[j];
        if (r >= 0) col[r] = j;
    }
    __syncthreads();
    if (tid < T_) {
        int cj = col[tid];
        int rank = 0;
        for (int t2 = 0; t2 < T_; ++t2) rank += (col[t2] < cj) ? 1 : 0;
        out_pred[b * T_ + rank] = (float)cj;
        out_tgt [b * T_ + rank] = (float)tid;
    }
}

extern "C" void kernel_launch(void* const* d_in, const int* in_sizes, int n_in,
                              void* d_out, int out_size, void* d_ws, size_t ws_size,
                              hipStream_t stream) {
    const float* logits  = (const float*)d_in[0];   // [B,Q,C]
    const float* pboxes  = (const float*)d_in[1];   // [B,Q,4]
    const int*   tlabels = (const int*)d_in[2];     // [B,T]
    const float* tboxes  = (const float*)d_in[3];   // [B,T,4]

    float* out      = (float*)d_out;
    float* cost     = out;                                   // [B,Q,T]
    float* out_pred = out + (size_t)B_ * Q_ * T_;            // [B,T]
    float* out_tgt  = out_pred + (size_t)B_ * T_;            // [B,T]

    float* costT = (float*)d_ws;  // [B,T,Q]; ws >= 23 MB proven

    dim3 gridc(TBLK, B_);
    cost_kernel<<<gridc, 256, 0, stream>>>(logits, pboxes, tlabels, tboxes, cost, costT);
    hung_kernel<<<B_, HB, 0, stream>>>(costT, out_pred, out_tgt);
}